// Round 1
// baseline (6952.862 us; speedup 1.0000x reference)
//
#include <hip/hip_runtime.h>
#include <math.h>
#include <cstddef>

// Problem constants
#define BB 2
#define TT 2048
#define CC 2048
#define HH 16
#define HD 128
#define MM (BB * TT)   // 4096 tokens

// ---------------------------------------------------------------------------
// K1: gating. One block per token. Computes argmax head + top1 softmax value.
// Must be fp32-exact-ish: argmax ties against the numpy ref would flip heads.
// ---------------------------------------------------------------------------
__global__ __launch_bounds__(256) void gate_kernel(const float* __restrict__ x,
                                                   const float* __restrict__ Wg,
                                                   int* __restrict__ idxbuf,
                                                   float* __restrict__ top1buf) {
    int m = blockIdx.x;
    int tid = threadIdx.x;
    int h = tid >> 4;      // 16 heads
    int j = tid & 15;      // 16 lanes per head
    const float4* xr = (const float4*)(x + (size_t)m * CC);
    const float4* wr = (const float4*)(Wg + (size_t)h * CC);
    float acc = 0.f;
#pragma unroll 8
    for (int i = 0; i < CC / 4; i += 16) {   // 512 float4 / 16 lanes = 32 iters
        float4 a = xr[i + j];
        float4 b = wr[i + j];
        acc += a.x * b.x + a.y * b.y + a.z * b.z + a.w * b.w;
    }
    // reduce across the 16 contiguous lanes of this head
    for (int off = 8; off > 0; off >>= 1) acc += __shfl_down(acc, off, 16);
    __shared__ float logits[HH];
    if (j == 0) logits[h] = acc;
    __syncthreads();
    if (tid == 0) {
        float zmax = logits[0];
        int best = 0;
        for (int i = 1; i < HH; i++) {
            if (logits[i] > zmax) { zmax = logits[i]; best = i; }  // strict >: first-max, numpy tie-break
        }
        float s = 0.f;
        for (int i = 0; i < HH; i++) s += expf(logits[i] - zmax);
        idxbuf[m] = best;
        top1buf[m] = 1.0f / s;   // softmax max value
    }
}

// ---------------------------------------------------------------------------
// K2: q projection, fp32 tiled GEMM. C[m,n] = sum_k A[m,k] * W[n,k]
// A = x [4096, 2048]; W = W_qkv rows [0, 2048). Output q [4096, 2048].
// BM=BN=128, BK=8, 256 threads, 8x8 micro-tile.
// ---------------------------------------------------------------------------
#define GBM 128
#define GBN 128
#define GBK 8
__global__ __launch_bounds__(256) void qproj_kernel(const float* __restrict__ A,
                                                    const float* __restrict__ W,
                                                    float* __restrict__ Cout) {
    __shared__ float As[GBK][GBM + 4];
    __shared__ float Bs[GBK][GBN + 4];
    int tid = threadIdx.x;
    int bn = blockIdx.x;   // 2048/128 = 16
    int bm = blockIdx.y;   // 4096/128 = 32
    int ty = tid >> 4;     // 0..15 -> rows ty*8..+7
    int tx = tid & 15;     // 0..15 -> cols tx*8..+7

    float acc[8][8];
#pragma unroll
    for (int i = 0; i < 8; i++)
#pragma unroll
        for (int j = 0; j < 8; j++) acc[i][j] = 0.f;

    // loader: 128 rows x 8 k = 1024 floats = 256 float4; 1 per thread
    int lr = tid >> 1;            // row in tile 0..127
    int lc = (tid & 1) * 4;       // k offset 0 or 4
    const float* Aptr = A + (size_t)(bm * GBM + lr) * CC + lc;
    const float* Wptr = W + (size_t)(bn * GBN + lr) * CC + lc;

    for (int k0 = 0; k0 < CC; k0 += GBK) {
        float4 a4 = *(const float4*)(Aptr + k0);
        float4 b4 = *(const float4*)(Wptr + k0);
        __syncthreads();
        As[lc + 0][lr] = a4.x; As[lc + 1][lr] = a4.y;
        As[lc + 2][lr] = a4.z; As[lc + 3][lr] = a4.w;
        Bs[lc + 0][lr] = b4.x; Bs[lc + 1][lr] = b4.y;
        Bs[lc + 2][lr] = b4.z; Bs[lc + 3][lr] = b4.w;
        __syncthreads();
#pragma unroll
        for (int k = 0; k < GBK; k++) {
            float4 a0 = *(const float4*)&As[k][ty * 8];
            float4 a1 = *(const float4*)&As[k][ty * 8 + 4];
            float4 b0 = *(const float4*)&Bs[k][tx * 8];
            float4 b1 = *(const float4*)&Bs[k][tx * 8 + 4];
            float av[8] = {a0.x, a0.y, a0.z, a0.w, a1.x, a1.y, a1.z, a1.w};
            float bv[8] = {b0.x, b0.y, b0.z, b0.w, b1.x, b1.y, b1.z, b1.w};
#pragma unroll
            for (int i = 0; i < 8; i++)
#pragma unroll
                for (int j = 0; j < 8; j++) acc[i][j] += av[i] * bv[j];
        }
    }
#pragma unroll
    for (int i = 0; i < 8; i++) {
        size_t row = (size_t)(bm * GBM + ty * 8 + i);
        float4 w0 = {acc[i][0], acc[i][1], acc[i][2], acc[i][3]};
        float4 w1 = {acc[i][4], acc[i][5], acc[i][6], acc[i][7]};
        float* dst = Cout + row * 2048 + bn * GBN + tx * 8;
        *(float4*)dst = w0;
        *(float4*)(dst + 4) = w1;
    }
}

// ---------------------------------------------------------------------------
// K3: k_shared / v_shared gather-projection. One block per token.
// ksh[m,d] = sum_c x[m,c] * Wqkv[2048 + idx*128 + d, c]
// vsh[m,d] = top1 * sum_c x[m,c] * Wqkv[4096 + idx*128 + d, c]
// 4 waves; each wave reduces outputs via 64-lane butterfly (coalesced W reads).
// ---------------------------------------------------------------------------
__global__ __launch_bounds__(256) void kv_gather_kernel(const float* __restrict__ x,
                                                        const float* __restrict__ Wqkv,
                                                        const int* __restrict__ idxbuf,
                                                        const float* __restrict__ top1buf,
                                                        float* __restrict__ ksh,
                                                        float* __restrict__ vsh) {
    __shared__ float xs[CC];
    int m = blockIdx.x;
    int tid = threadIdx.x;
    const float4* xr = (const float4*)(x + (size_t)m * CC);
    float4* xs4 = (float4*)xs;
    xs4[tid] = xr[tid];
    xs4[tid + 256] = xr[tid + 256];
    __syncthreads();
    int hsel = idxbuf[m];
    float tv = top1buf[m];
    int wave = tid >> 6;
    int lane = tid & 63;
    // wave handles outputs d = wave*64 .. +63; two at a time for ILP
    for (int o = 0; o < 32; o++) {
        int d0 = wave * 64 + o;
        int d1 = d0 + 32;
        int wrow0 = (d0 < 128) ? (2048 + hsel * 128 + d0) : (4096 + hsel * 128 + (d0 - 128));
        int wrow1 = (d1 < 128) ? (2048 + hsel * 128 + d1) : (4096 + hsel * 128 + (d1 - 128));
        const float4* wr0 = (const float4*)(Wqkv + (size_t)wrow0 * CC);
        const float4* wr1 = (const float4*)(Wqkv + (size_t)wrow1 * CC);
        float acc0 = 0.f, acc1 = 0.f;
#pragma unroll
        for (int i = lane; i < CC / 4; i += 64) {   // 8 iters
            float4 a = xs4[i];
            float4 b0 = wr0[i];
            float4 b1 = wr1[i];
            acc0 += a.x * b0.x + a.y * b0.y + a.z * b0.z + a.w * b0.w;
            acc1 += a.x * b1.x + a.y * b1.y + a.z * b1.z + a.w * b1.w;
        }
        for (int off = 32; off > 0; off >>= 1) {
            acc0 += __shfl_xor(acc0, off);
            acc1 += __shfl_xor(acc1, off);
        }
        if (lane == 0) {
            if (d0 < 128) ksh[(size_t)m * HD + d0] = acc0;
            else          vsh[(size_t)m * HD + (d0 - 128)] = acc0 * tv;
            if (d1 < 128) ksh[(size_t)m * HD + d1] = acc1;
            else          vsh[(size_t)m * HD + (d1 - 128)] = acc1 * tv;
        }
    }
}

// ---------------------------------------------------------------------------
// K4: flash-style causal attention, fp32. One block per (b, h, 16-row q-tile).
// Shared K/V across heads (MQA). Online softmax. 42 KB LDS -> ~3 blocks/CU.
// ---------------------------------------------------------------------------
#define BQ 16
#define BKC 32
__global__ __launch_bounds__(256) void attn_kernel(const float* __restrict__ qbuf, // [M, 2048]
                                                   const float* __restrict__ ksh,  // [M, 128]
                                                   const float* __restrict__ vsh,  // [M, 128]
                                                   float* __restrict__ y) {        // [M, 2048]
    __shared__ float Qs[BQ][HD];    // 8 KB
    __shared__ float Ks[BKC][HD];   // 16 KB
    __shared__ float Vs[BKC][HD];   // 16 KB
    __shared__ float Sb[BQ][BKC];   // 2 KB

    int bid = blockIdx.x;
    int qt = bid & 127;          // T/BQ = 128
    int h = (bid >> 7) & 15;
    int b = bid >> 11;
    int q0 = qt * BQ;
    int tid = threadIdx.x;
    int r = tid >> 4;            // q row within tile 0..15
    int l16 = tid & 15;

    const float scale = 0.08838834764831845f;  // 1/sqrt(128)
    // load Q tile (pre-scaled): 16 rows x 128 = 512 float4, 2 per thread
    {
        int f = tid;
#pragma unroll
        for (int rep = 0; rep < 2; rep++, f += 256) {
            int rr = f >> 5, c4 = f & 31;
            float4 v = *(const float4*)(qbuf + (size_t)(b * TT + q0 + rr) * 2048 + h * HD + c4 * 4);
            v.x *= scale; v.y *= scale; v.z *= scale; v.w *= scale;
            *(float4*)&Qs[rr][c4 * 4] = v;
        }
    }

    float m_r = -1e30f, l_r = 0.f;
    float o[8] = {0.f, 0.f, 0.f, 0.f, 0.f, 0.f, 0.f, 0.f};
    int qg = q0 + r;             // this row's global query index
    int kend = q0 + BQ;

    for (int kc0 = 0; kc0 < kend; kc0 += BKC) {
        __syncthreads();   // prev PV done (and, first iter, Qs loaded)
        // load K/V chunk: 32 rows x 32 float4 = 1024 float4, 4 per thread
        {
            int f = tid;
#pragma unroll
            for (int rep = 0; rep < 4; rep++, f += 256) {
                int kk = f >> 5, c4 = f & 31;
                size_t g = (size_t)(b * TT + kc0 + kk) * HD + c4 * 4;
                *(float4*)&Ks[kk][c4 * 4] = *(const float4*)(ksh + g);
                *(float4*)&Vs[kk][c4 * 4] = *(const float4*)(vsh + g);
            }
        }
        __syncthreads();
        // scores: thread computes keys k0 = l16*2, +1 for row r
        int k0 = l16 * 2, k1 = k0 + 1;
        float s0 = 0.f, s1 = 0.f;
#pragma unroll
        for (int c = 0; c < HD; c += 4) {
            float4 qv = *(const float4*)&Qs[r][c];
            float4 ka = *(const float4*)&Ks[k0][c];
            float4 kb = *(const float4*)&Ks[k1][c];
            s0 += qv.x * ka.x + qv.y * ka.y + qv.z * ka.z + qv.w * ka.w;
            s1 += qv.x * kb.x + qv.y * kb.y + qv.z * kb.z + qv.w * kb.w;
        }
        if (kc0 + k0 > qg) s0 = -1e30f;
        if (kc0 + k1 > qg) s1 = -1e30f;
        // online softmax over this row's 32 scores (16-lane butterfly)
        float tmax = fmaxf(s0, s1);
        for (int off = 8; off > 0; off >>= 1) tmax = fmaxf(tmax, __shfl_xor(tmax, off, 16));
        float newm = fmaxf(m_r, tmax);
        float alpha = expf(m_r - newm);
        float p0 = expf(s0 - newm);
        float p1 = expf(s1 - newm);
        Sb[r][k0] = p0;
        Sb[r][k1] = p1;
        float psum = p0 + p1;
        for (int off = 8; off > 0; off >>= 1) psum += __shfl_xor(psum, off, 16);
        l_r = l_r * alpha + psum;
        m_r = newm;
#pragma unroll
        for (int i = 0; i < 8; i++) o[i] *= alpha;
        __syncthreads();   // Sb visible
        // PV: thread accumulates dims d = l16*8 .. +7 for row r
#pragma unroll 4
        for (int k = 0; k < BKC; k++) {
            float p = Sb[r][k];
            float4 va = *(const float4*)&Vs[k][l16 * 8];
            float4 vb = *(const float4*)&Vs[k][l16 * 8 + 4];
            o[0] += p * va.x; o[1] += p * va.y; o[2] += p * va.z; o[3] += p * va.w;
            o[4] += p * vb.x; o[5] += p * vb.y; o[6] += p * vb.z; o[7] += p * vb.w;
        }
    }
    float inv = 1.0f / l_r;
    float4 r0 = {o[0] * inv, o[1] * inv, o[2] * inv, o[3] * inv};
    float4 r1 = {o[4] * inv, o[5] * inv, o[6] * inv, o[7] * inv};
    float* dst = y + (size_t)(b * TT + qg) * 2048 + h * HD + l16 * 8;
    *(float4*)dst = r0;
    *(float4*)(dst + 4) = r1;
}

// ---------------------------------------------------------------------------
// Launcher. Workspace layout (floats unless noted), total ~37.8 MB:
//   qbuf  [4096*2048]  33.55 MB
//   ksh   [4096*128]    2.10 MB
//   vsh   [4096*128]    2.10 MB
//   top1  [4096]        16 KB
//   idx   [4096] int    16 KB
// ---------------------------------------------------------------------------
extern "C" void kernel_launch(void* const* d_in, const int* in_sizes, int n_in,
                              void* d_out, int out_size, void* d_ws, size_t ws_size,
                              hipStream_t stream) {
    (void)in_sizes; (void)n_in; (void)out_size; (void)ws_size;
    const float* x    = (const float*)d_in[0];
    const float* Wg   = (const float*)d_in[1];
    const float* Wqkv = (const float*)d_in[2];
    float* y = (float*)d_out;

    float* qbuf = (float*)d_ws;
    float* kshb = qbuf + (size_t)MM * 2048;
    float* vshb = kshb + (size_t)MM * HD;
    float* top1 = vshb + (size_t)MM * HD;
    int*   idxb = (int*)(top1 + MM);

    gate_kernel<<<MM, 256, 0, stream>>>(x, Wg, idxb, top1);
    qproj_kernel<<<dim3(16, 32), 256, 0, stream>>>(x, Wqkv, qbuf);
    kv_gather_kernel<<<MM, 256, 0, stream>>>(x, Wqkv, idxb, top1, kshb, vshb);
    attn_kernel<<<BB * HH * (TT / BQ), 256, 0, stream>>>(qbuf, kshb, vshb, y);
}

// Round 2
// 1238.603 us; speedup vs baseline: 5.6135x; 5.6135x over previous
//
#include <hip/hip_runtime.h>
#include <math.h>
#include <cstddef>

// Problem constants
#define BB 2
#define TT 2048
#define CC 2048
#define HH 16
#define HD 128
#define MM (BB * TT)   // 4096 tokens

typedef __attribute__((ext_vector_type(8))) short short8;
typedef __attribute__((ext_vector_type(4))) float f32x4;

__device__ __forceinline__ unsigned short f2bf(float f) {
    union { float f; unsigned int u; } v; v.f = f;
    unsigned int r = v.u + 0x7FFFu + ((v.u >> 16) & 1u);  // RNE
    return (unsigned short)(r >> 16);
}

// ---------------------------------------------------------------------------
// K1: gating. One block per token. fp32 exact-ish (argmax ties must match np).
// ---------------------------------------------------------------------------
__global__ __launch_bounds__(256) void gate_kernel(const float* __restrict__ x,
                                                   const float* __restrict__ Wg,
                                                   int* __restrict__ idxbuf,
                                                   float* __restrict__ top1buf) {
    int m = blockIdx.x;
    int tid = threadIdx.x;
    int h = tid >> 4;
    int j = tid & 15;
    const float4* xr = (const float4*)(x + (size_t)m * CC);
    const float4* wr = (const float4*)(Wg + (size_t)h * CC);
    float acc = 0.f;
#pragma unroll 8
    for (int i = 0; i < CC / 4; i += 16) {
        float4 a = xr[i + j];
        float4 b = wr[i + j];
        acc += a.x * b.x + a.y * b.y + a.z * b.z + a.w * b.w;
    }
    for (int off = 8; off > 0; off >>= 1) acc += __shfl_down(acc, off, 16);
    __shared__ float logits[HH];
    if (j == 0) logits[h] = acc;
    __syncthreads();
    if (tid == 0) {
        float zmax = logits[0];
        int best = 0;
        for (int i = 1; i < HH; i++) {
            if (logits[i] > zmax) { zmax = logits[i]; best = i; }
        }
        float s = 0.f;
        for (int i = 0; i < HH; i++) s += expf(logits[i] - zmax);
        idxbuf[m] = best;
        top1buf[m] = 1.0f / s;
    }
}

// ---------------------------------------------------------------------------
// K2: q projection fp32 GEMM -> bf16 output, pre-scaled by 1/sqrt(hd).
// ---------------------------------------------------------------------------
#define GBM 128
#define GBN 128
#define GBK 8
__global__ __launch_bounds__(256) void qproj_kernel(const float* __restrict__ A,
                                                    const float* __restrict__ W,
                                                    unsigned short* __restrict__ Cout) {
    __shared__ float As[GBK][GBM + 4];
    __shared__ float Bs[GBK][GBN + 4];
    int tid = threadIdx.x;
    int bn = blockIdx.x;
    int bm = blockIdx.y;
    int ty = tid >> 4;
    int tx = tid & 15;

    float acc[8][8];
#pragma unroll
    for (int i = 0; i < 8; i++)
#pragma unroll
        for (int j = 0; j < 8; j++) acc[i][j] = 0.f;

    int lr = tid >> 1;
    int lc = (tid & 1) * 4;
    const float* Aptr = A + (size_t)(bm * GBM + lr) * CC + lc;
    const float* Wptr = W + (size_t)(bn * GBN + lr) * CC + lc;

    for (int k0 = 0; k0 < CC; k0 += GBK) {
        float4 a4 = *(const float4*)(Aptr + k0);
        float4 b4 = *(const float4*)(Wptr + k0);
        __syncthreads();
        As[lc + 0][lr] = a4.x; As[lc + 1][lr] = a4.y;
        As[lc + 2][lr] = a4.z; As[lc + 3][lr] = a4.w;
        Bs[lc + 0][lr] = b4.x; Bs[lc + 1][lr] = b4.y;
        Bs[lc + 2][lr] = b4.z; Bs[lc + 3][lr] = b4.w;
        __syncthreads();
#pragma unroll
        for (int k = 0; k < GBK; k++) {
            float4 a0 = *(const float4*)&As[k][ty * 8];
            float4 a1 = *(const float4*)&As[k][ty * 8 + 4];
            float4 b0 = *(const float4*)&Bs[k][tx * 8];
            float4 b1 = *(const float4*)&Bs[k][tx * 8 + 4];
            float av[8] = {a0.x, a0.y, a0.z, a0.w, a1.x, a1.y, a1.z, a1.w};
            float bv[8] = {b0.x, b0.y, b0.z, b0.w, b1.x, b1.y, b1.z, b1.w};
#pragma unroll
            for (int i = 0; i < 8; i++)
#pragma unroll
                for (int j = 0; j < 8; j++) acc[i][j] += av[i] * bv[j];
        }
    }
    const float qscale = 0.08838834764831845f;  // 1/sqrt(128)
#pragma unroll
    for (int i = 0; i < 8; i++) {
        size_t row = (size_t)(bm * GBM + ty * 8 + i);
        union { unsigned short s[8]; uint4 u; } pk;
#pragma unroll
        for (int j = 0; j < 8; j++) pk.s[j] = f2bf(acc[i][j] * qscale);
        unsigned short* dst = Cout + row * 2048 + bn * GBN + tx * 8;
        *(uint4*)dst = pk.u;
    }
}

// ---------------------------------------------------------------------------
// K3: k_shared / v_shared gather-projection -> bf16.
// kshB[m][d]   = sum_c x[m,c] * Wqkv[2048 + idx*128 + d, c]
// vshT[d][m]   = top1 * sum_c x[m,c] * Wqkv[4096 + idx*128 + d, c]  (transposed!)
// ---------------------------------------------------------------------------
__global__ __launch_bounds__(256) void kv_gather_kernel(const float* __restrict__ x,
                                                        const float* __restrict__ Wqkv,
                                                        const int* __restrict__ idxbuf,
                                                        const float* __restrict__ top1buf,
                                                        unsigned short* __restrict__ kshB,
                                                        unsigned short* __restrict__ vshT) {
    __shared__ float xs[CC];
    int m = blockIdx.x;
    int tid = threadIdx.x;
    const float4* xr = (const float4*)(x + (size_t)m * CC);
    float4* xs4 = (float4*)xs;
    xs4[tid] = xr[tid];
    xs4[tid + 256] = xr[tid + 256];
    __syncthreads();
    int hsel = idxbuf[m];
    float tv = top1buf[m];
    int wave = tid >> 6;
    int lane = tid & 63;
    for (int o = 0; o < 32; o++) {
        int d0 = wave * 64 + o;
        int d1 = d0 + 32;
        int wrow0 = (d0 < 128) ? (2048 + hsel * 128 + d0) : (4096 + hsel * 128 + (d0 - 128));
        int wrow1 = (d1 < 128) ? (2048 + hsel * 128 + d1) : (4096 + hsel * 128 + (d1 - 128));
        const float4* wr0 = (const float4*)(Wqkv + (size_t)wrow0 * CC);
        const float4* wr1 = (const float4*)(Wqkv + (size_t)wrow1 * CC);
        float acc0 = 0.f, acc1 = 0.f;
#pragma unroll
        for (int i = lane; i < CC / 4; i += 64) {
            float4 a = xs4[i];
            float4 b0 = wr0[i];
            float4 b1 = wr1[i];
            acc0 += a.x * b0.x + a.y * b0.y + a.z * b0.z + a.w * b0.w;
            acc1 += a.x * b1.x + a.y * b1.y + a.z * b1.z + a.w * b1.w;
        }
        for (int off = 32; off > 0; off >>= 1) {
            acc0 += __shfl_xor(acc0, off);
            acc1 += __shfl_xor(acc1, off);
        }
        if (lane == 0) {
            if (d0 < 128) kshB[(size_t)m * HD + d0] = f2bf(acc0);
            else          vshT[(size_t)(d0 - 128) * MM + m] = f2bf(acc0 * tv);
            if (d1 < 128) kshB[(size_t)m * HD + d1] = f2bf(acc1);
            else          vshT[(size_t)(d1 - 128) * MM + m] = f2bf(acc1 * tv);
        }
    }
}

// ---------------------------------------------------------------------------
// K4: MFMA bf16 flash attention. Block = 256 thr = 4 waves; each wave owns
// 16 q-rows (BQ=64/block). K/V chunk of 64 keys staged to LDS as bf16.
// MFMA 16x16x32: A[m=lane&15][k=(lane>>4)*8+j], B[n=lane&15][k], D col=lane&15,
// row=(lane>>4)*4+reg. P round-trips LDS (C-layout -> A-layout). All LDS
// strides give <=2-way bank aliasing (free).
// ---------------------------------------------------------------------------
__global__ __launch_bounds__(256) void attn_mfma(const unsigned short* __restrict__ qb,   // [M][2048] bf16 (pre-scaled)
                                                 const unsigned short* __restrict__ kb,   // [M][128] bf16
                                                 const unsigned short* __restrict__ vtb,  // [128][M] bf16
                                                 float* __restrict__ y) {                 // [M][2048] fp32
    __shared__ unsigned short Ks[64][136];   // 17408 B, row stride 272B: frag reads 2-way
    __shared__ unsigned short Vt[128][72];   // 18432 B, row stride 144B: frag reads 2-way
    __shared__ unsigned short Ps[4][16][72]; //  9216 B, per-wave P buffer

    int bid = blockIdx.x;
    int qt = 31 - (bid & 31);          // longest q-tiles dispatch first (load balance)
    int bh = bid >> 5;
    int h = bh & 15;
    int b = bh >> 4;
    int q0 = qt * 64;
    int tid = threadIdx.x;
    int wave = tid >> 6;
    int lane = tid & 63;
    int l = lane & 15;
    int g = lane >> 4;

    // Q a-frags straight from global (bf16, pre-scaled), once per block.
    short8 qf[4];
    {
        const unsigned short* qrowp = qb + (size_t)(b * TT + q0 + wave * 16 + l) * CC + h * HD;
#pragma unroll
        for (int kc = 0; kc < 4; kc++)
            qf[kc] = *(const short8*)(qrowp + kc * 32 + g * 8);
    }

    f32x4 o[8];
#pragma unroll
    for (int n = 0; n < 8; n++) o[n] = (f32x4){0.f, 0.f, 0.f, 0.f};
    float mrow[4] = {-1e30f, -1e30f, -1e30f, -1e30f};
    float lrow[4] = {0.f, 0.f, 0.f, 0.f};

    int kend = q0 + 64;
    for (int kc0 = 0; kc0 < kend; kc0 += 64) {
        __syncthreads();   // previous chunk's LDS reads done
        // stage K: 64 keys x 128 dims bf16, 1024 x 16B, 4 per thread (coalesced)
#pragma unroll
        for (int rep = 0; rep < 4; rep++) {
            int f = tid + rep * 256;
            int row = f >> 4, c8 = f & 15;
            uint4 d = *(const uint4*)(kb + (size_t)(b * TT + kc0 + row) * HD + c8 * 8);
            *(uint4*)&Ks[row][c8 * 8] = d;
        }
        // stage Vt: 128 dims x 64 keys (source already transposed -> coalesced)
#pragma unroll
        for (int rep = 0; rep < 4; rep++) {
            int f = tid + rep * 256;
            int dd = f >> 3, k8 = f & 7;
            uint4 d = *(const uint4*)(vtb + (size_t)dd * MM + b * TT + kc0 + k8 * 8);
            *(uint4*)&Vt[dd][k8 * 8] = d;
        }
        __syncthreads();

        // S = Q K^T : 4 key-tiles of 16, K-dim 128 = 4 MFMAs each
        f32x4 st[4];
#pragma unroll
        for (int t = 0; t < 4; t++) {
            f32x4 acc = (f32x4){0.f, 0.f, 0.f, 0.f};
#pragma unroll
            for (int kc = 0; kc < 4; kc++) {
                short8 bf = *(const short8*)&Ks[t * 16 + l][kc * 32 + g * 8];
                acc = __builtin_amdgcn_mfma_f32_16x16x32_bf16(qf[kc], bf, acc, 0, 0, 0);
            }
            st[t] = acc;
        }
        // causal mask (D layout: row = rbase+i, col/key = kc0+16t+l)
        int rbase = q0 + wave * 16 + g * 4;
#pragma unroll
        for (int t = 0; t < 4; t++) {
            int key = kc0 + t * 16 + l;
#pragma unroll
            for (int i = 0; i < 4; i++)
                if (key > rbase + i) st[t][i] = -1e30f;
        }
        // online softmax (row r lives in the 16 lanes of group g, reg i)
        float nm[4], al[4], ps[4];
#pragma unroll
        for (int i = 0; i < 4; i++) {
            float tm = fmaxf(fmaxf(st[0][i], st[1][i]), fmaxf(st[2][i], st[3][i]));
            tm = fmaxf(tm, __shfl_xor(tm, 1));
            tm = fmaxf(tm, __shfl_xor(tm, 2));
            tm = fmaxf(tm, __shfl_xor(tm, 4));
            tm = fmaxf(tm, __shfl_xor(tm, 8));
            nm[i] = fmaxf(mrow[i], tm);
            al[i] = __expf(mrow[i] - nm[i]);
            mrow[i] = nm[i];
            ps[i] = 0.f;
        }
#pragma unroll
        for (int t = 0; t < 4; t++) {
#pragma unroll
            for (int i = 0; i < 4; i++) {
                float p = __expf(st[t][i] - nm[i]);
                ps[i] += p;
                Ps[wave][g * 4 + i][t * 16 + l] = f2bf(p);
            }
        }
#pragma unroll
        for (int i = 0; i < 4; i++) {
            float s = ps[i];
            s += __shfl_xor(s, 1);
            s += __shfl_xor(s, 2);
            s += __shfl_xor(s, 4);
            s += __shfl_xor(s, 8);
            lrow[i] = lrow[i] * al[i] + s;
#pragma unroll
            for (int n = 0; n < 8; n++) o[n][i] *= al[i];
        }
        // O += P V  (per-wave P; same-wave DS ordering makes this safe w/o barrier)
#pragma unroll
        for (int kc2 = 0; kc2 < 2; kc2++) {
            short8 pf = *(const short8*)&Ps[wave][l][kc2 * 32 + g * 8];
#pragma unroll
            for (int n = 0; n < 8; n++) {
                short8 vf = *(const short8*)&Vt[n * 16 + l][kc2 * 32 + g * 8];
                o[n] = __builtin_amdgcn_mfma_f32_16x16x32_bf16(pf, vf, o[n], 0, 0, 0);
            }
        }
    }
    float inv[4];
#pragma unroll
    for (int i = 0; i < 4; i++) inv[i] = 1.f / lrow[i];
#pragma unroll
    for (int n = 0; n < 8; n++) {
#pragma unroll
        for (int i = 0; i < 4; i++) {
            y[(size_t)(b * TT + q0 + wave * 16 + g * 4 + i) * CC + h * HD + n * 16 + l] =
                o[n][i] * inv[i];
        }
    }
}

// ---------------------------------------------------------------------------
// Launcher. Workspace (~19 MB):
//   qbufB  ushort [4096*2048]  16.78 MB
//   kshB   ushort [4096*128]    1.05 MB
//   vshT   ushort [128*4096]    1.05 MB
//   top1   float  [4096], idx int [4096]
// ---------------------------------------------------------------------------
extern "C" void kernel_launch(void* const* d_in, const int* in_sizes, int n_in,
                              void* d_out, int out_size, void* d_ws, size_t ws_size,
                              hipStream_t stream) {
    (void)in_sizes; (void)n_in; (void)out_size; (void)ws_size;
    const float* x    = (const float*)d_in[0];
    const float* Wg   = (const float*)d_in[1];
    const float* Wqkv = (const float*)d_in[2];
    float* y = (float*)d_out;

    unsigned short* qbufB = (unsigned short*)d_ws;
    unsigned short* kshB  = qbufB + (size_t)MM * CC;
    unsigned short* vshT  = kshB + (size_t)MM * HD;
    float* top1 = (float*)(vshT + (size_t)HD * MM);
    int*   idxb = (int*)(top1 + MM);

    gate_kernel<<<MM, 256, 0, stream>>>(x, Wg, idxb, top1);
    qproj_kernel<<<dim3(16, 32), 256, 0, stream>>>(x, Wqkv, qbufB);
    kv_gather_kernel<<<MM, 256, 0, stream>>>(x, Wqkv, idxb, top1, kshB, vshT);
    attn_mfma<<<BB * HH * (TT / 64), 256, 0, stream>>>(qbufB, kshB, vshT, y);
}

// Round 3
// 556.649 us; speedup vs baseline: 12.4906x; 2.2251x over previous
//
#include <hip/hip_runtime.h>
#include <math.h>
#include <cstddef>

// Problem constants
#define BB 2
#define TT 2048
#define CC 2048
#define HH 16
#define HD 128
#define MM (BB * TT)   // 4096 tokens
#define QKV_N 6144
#define BK 32

typedef __attribute__((ext_vector_type(8))) short short8;
typedef __attribute__((ext_vector_type(4))) float f32x4;

__device__ __forceinline__ unsigned short f2bf(float f) {
    union { float f; unsigned int u; } v; v.f = f;
    unsigned int r = v.u + 0x7FFFu + ((v.u >> 16) & 1u);  // RNE
    return (unsigned short)(r >> 16);
}
__device__ __forceinline__ float bf2f(unsigned short s) {
    union { unsigned int u; float f; } v; v.u = ((unsigned int)s) << 16;
    return v.f;
}
__device__ __forceinline__ void gload16(const void* g, void* l) {
    __builtin_amdgcn_global_load_lds(
        (const __attribute__((address_space(1))) unsigned int*)g,
        (__attribute__((address_space(3))) unsigned int*)l, 16, 0, 0);
}

// ---------------------------------------------------------------------------
// K1: gating. One block per token. fp32 (argmax ties must match np).
// ---------------------------------------------------------------------------
__global__ __launch_bounds__(256) void gate_kernel(const float* __restrict__ x,
                                                   const float* __restrict__ Wg,
                                                   int* __restrict__ idxbuf,
                                                   float* __restrict__ top1buf) {
    int m = blockIdx.x;
    int tid = threadIdx.x;
    int h = tid >> 4;
    int j = tid & 15;
    const float4* xr = (const float4*)(x + (size_t)m * CC);
    const float4* wr = (const float4*)(Wg + (size_t)h * CC);
    float acc = 0.f;
#pragma unroll 8
    for (int i = 0; i < CC / 4; i += 16) {
        float4 a = xr[i + j];
        float4 b = wr[i + j];
        acc += a.x * b.x + a.y * b.y + a.z * b.z + a.w * b.w;
    }
    for (int off = 8; off > 0; off >>= 1) acc += __shfl_down(acc, off, 16);
    __shared__ float logits[HH];
    if (j == 0) logits[h] = acc;
    __syncthreads();
    if (tid == 0) {
        float zmax = logits[0];
        int best = 0;
        for (int i = 1; i < HH; i++) {
            if (logits[i] > zmax) { zmax = logits[i]; best = i; }
        }
        float s = 0.f;
        for (int i = 0; i < HH; i++) s += expf(logits[i] - zmax);
        idxbuf[m] = best;
        top1buf[m] = 1.0f / s;
    }
}

// ---------------------------------------------------------------------------
// K2: fp32 -> bf16 convert (8 elems/thread, 16B stores).
// ---------------------------------------------------------------------------
__global__ __launch_bounds__(256) void convert_bf16(const float* __restrict__ src,
                                                    unsigned short* __restrict__ dst,
                                                    int n8) {
    int i = blockIdx.x * 256 + threadIdx.x;
    if (i >= n8) return;
    const float4* s4 = (const float4*)src;
    float4 a = s4[i * 2], b = s4[i * 2 + 1];
    union { unsigned short s[8]; uint4 u; } pk;
    pk.s[0] = f2bf(a.x); pk.s[1] = f2bf(a.y); pk.s[2] = f2bf(a.z); pk.s[3] = f2bf(a.w);
    pk.s[4] = f2bf(b.x); pk.s[5] = f2bf(b.y); pk.s[6] = f2bf(b.z); pk.s[7] = f2bf(b.w);
    ((uint4*)dst)[i] = pk.u;
}

// ---------------------------------------------------------------------------
// K3: qkv = xb @ wbT, bf16 MFMA GEMM (m97 structure).
// 128x128 tile, BK=32, 4 waves (2x2), each wave 64x64 via 4x4 16x16x32 MFMAs.
// Staging via global_load_lds width=16 into unpadded row-major [128][32] LDS.
// Epilogue: bf16 store; cols < 2048 (q region) pre-scaled by 1/sqrt(128).
// ---------------------------------------------------------------------------
__global__ __launch_bounds__(256) void qkv_gemm(const unsigned short* __restrict__ A,  // [M][2048] bf16
                                                const unsigned short* __restrict__ Bm, // [N][2048] bf16
                                                unsigned short* __restrict__ C) {      // [M][6144] bf16
    __shared__ unsigned short As[128 * BK];  // 8 KB
    __shared__ unsigned short Bs[128 * BK];  // 8 KB
    int tid = threadIdx.x;
    int wave = tid >> 6, lane = tid & 63;
    int l = lane & 15, g = lane >> 4;
    int m0 = blockIdx.y * 128, n0 = blockIdx.x * 128;
    int wr = wave >> 1, wc = wave & 1;

    f32x4 acc[4][4];
#pragma unroll
    for (int i = 0; i < 4; i++)
#pragma unroll
        for (int j = 0; j < 4; j++) acc[i][j] = (f32x4){0.f, 0.f, 0.f, 0.f};

    // staging: wave covers rows wave*32 .. wave*32+31 (two 16-row chunks)
    int srow = lane >> 2;            // 0..15
    int scol = (lane & 3) * 8;       // 0,8,16,24
    const unsigned short* aB0 = A + (size_t)(m0 + wave * 32 + srow) * 2048 + scol;
    const unsigned short* bB0 = Bm + (size_t)(n0 + wave * 32 + srow) * 2048 + scol;
    unsigned short* aL0 = &As[wave * 1024];
    unsigned short* bL0 = &Bs[wave * 1024];

    for (int k0 = 0; k0 < 2048; k0 += BK) {
        __syncthreads();   // previous iteration's LDS reads done
        gload16(aB0 + k0, aL0);
        gload16(aB0 + k0 + (size_t)16 * 2048, aL0 + 512);
        gload16(bB0 + k0, bL0);
        gload16(bB0 + k0 + (size_t)16 * 2048, bL0 + 512);
        __syncthreads();   // staging visible (vmcnt drained by barrier)
        short8 af[4], bf[4];
#pragma unroll
        for (int i = 0; i < 4; i++)
            af[i] = *(const short8*)&As[(wr * 64 + i * 16 + l) * BK + g * 8];
#pragma unroll
        for (int j = 0; j < 4; j++)
            bf[j] = *(const short8*)&Bs[(wc * 64 + j * 16 + l) * BK + g * 8];
#pragma unroll
        for (int i = 0; i < 4; i++)
#pragma unroll
            for (int j = 0; j < 4; j++)
                acc[i][j] = __builtin_amdgcn_mfma_f32_16x16x32_bf16(af[i], bf[j], acc[i][j], 0, 0, 0);
    }

    const float qscale = 0.08838834764831845f;  // 1/sqrt(128)
#pragma unroll
    for (int j = 0; j < 4; j++) {
        int col = n0 + wc * 64 + j * 16 + l;
        float s = (col < 2048) ? qscale : 1.0f;
#pragma unroll
        for (int i = 0; i < 4; i++) {
            int row = m0 + wr * 64 + i * 16 + g * 4;
#pragma unroll
            for (int r = 0; r < 4; r++)
                C[(size_t)(row + r) * QKV_N + col] = f2bf(acc[i][j][r] * s);
        }
    }
}

// ---------------------------------------------------------------------------
// K4: gather selected head's k/v from qkv buffer.
// kshB[m][d] = qkv[m][2048 + idx*128 + d]
// vshT[d][m] = top1 * qkv[m][4096 + idx*128 + d]   (transposed via LDS)
// Block = 256 thr handles 64 tokens.
// ---------------------------------------------------------------------------
__global__ __launch_bounds__(256) void kv_gather2(const unsigned short* __restrict__ qkv,
                                                  const int* __restrict__ idxb,
                                                  const float* __restrict__ top1,
                                                  unsigned short* __restrict__ kshB,
                                                  unsigned short* __restrict__ vshT) {
    __shared__ unsigned short Vs[64][136];
    int m0 = blockIdx.x * 64;
    int tid = threadIdx.x;
    int tok = tid >> 2;          // 4 threads per token
    int c4 = tid & 3;            // each handles 4 uint4 (64 dims... 4*4*8=128 total)
    int m = m0 + tok;
    int hs = idxb[m];
    float tv = top1[m];
    const uint4* krow = (const uint4*)(qkv + (size_t)m * QKV_N + 2048 + hs * 128);
    const uint4* vrow = (const uint4*)(qkv + (size_t)m * QKV_N + 4096 + hs * 128);
    uint4* kdst = (uint4*)(kshB + (size_t)m * HD);
#pragma unroll
    for (int u = 0; u < 4; u++) kdst[c4 * 4 + u] = krow[c4 * 4 + u];
#pragma unroll
    for (int u = 0; u < 4; u++) {
        uint4 d = vrow[c4 * 4 + u];
        unsigned short* ss = (unsigned short*)&d;
        union { unsigned short s[8]; uint4 u4; } pk;
#pragma unroll
        for (int e = 0; e < 8; e++) pk.s[e] = f2bf(bf2f(ss[e]) * tv);
        *(uint4*)&Vs[tok][(c4 * 4 + u) * 8] = pk.u4;
    }
    __syncthreads();
    // transpose out: thread -> dim d = tid>>1, token-half = tid&1 (32 tokens)
    int d = tid >> 1, half = tid & 1;
#pragma unroll
    for (int u = 0; u < 4; u++) {
        union { unsigned short s[8]; uint4 u4; } pk;
#pragma unroll
        for (int e = 0; e < 8; e++) pk.s[e] = Vs[half * 32 + u * 8 + e][d];
        *(uint4*)(vshT + (size_t)d * MM + m0 + half * 32 + u * 8) = pk.u4;
    }
}

// ---------------------------------------------------------------------------
// K5: MFMA bf16 flash attention (unchanged from R2 except q stride = 6144).
// ---------------------------------------------------------------------------
__global__ __launch_bounds__(256) void attn_mfma(const unsigned short* __restrict__ qb,   // [M][6144] bf16, q pre-scaled
                                                 const unsigned short* __restrict__ kb,   // [M][128] bf16
                                                 const unsigned short* __restrict__ vtb,  // [128][M] bf16
                                                 float* __restrict__ y) {                 // [M][2048] fp32
    __shared__ unsigned short Ks[64][136];
    __shared__ unsigned short Vt[128][72];
    __shared__ unsigned short Ps[4][16][72];

    int bid = blockIdx.x;
    int qt = 31 - (bid & 31);          // longest q-tiles first
    int bh = bid >> 5;
    int h = bh & 15;
    int b = bh >> 4;
    int q0 = qt * 64;
    int tid = threadIdx.x;
    int wave = tid >> 6;
    int lane = tid & 63;
    int l = lane & 15;
    int g = lane >> 4;

    short8 qf[4];
    {
        const unsigned short* qrowp = qb + (size_t)(b * TT + q0 + wave * 16 + l) * QKV_N + h * HD;
#pragma unroll
        for (int kc = 0; kc < 4; kc++)
            qf[kc] = *(const short8*)(qrowp + kc * 32 + g * 8);
    }

    f32x4 o[8];
#pragma unroll
    for (int n = 0; n < 8; n++) o[n] = (f32x4){0.f, 0.f, 0.f, 0.f};
    float mrow[4] = {-1e30f, -1e30f, -1e30f, -1e30f};
    float lrow[4] = {0.f, 0.f, 0.f, 0.f};

    int kend = q0 + 64;
    for (int kc0 = 0; kc0 < kend; kc0 += 64) {
        __syncthreads();
#pragma unroll
        for (int rep = 0; rep < 4; rep++) {
            int f = tid + rep * 256;
            int row = f >> 4, c8 = f & 15;
            uint4 d = *(const uint4*)(kb + (size_t)(b * TT + kc0 + row) * HD + c8 * 8);
            *(uint4*)&Ks[row][c8 * 8] = d;
        }
#pragma unroll
        for (int rep = 0; rep < 4; rep++) {
            int f = tid + rep * 256;
            int dd = f >> 3, k8 = f & 7;
            uint4 d = *(const uint4*)(vtb + (size_t)dd * MM + b * TT + kc0 + k8 * 8);
            *(uint4*)&Vt[dd][k8 * 8] = d;
        }
        __syncthreads();

        f32x4 st[4];
#pragma unroll
        for (int t = 0; t < 4; t++) {
            f32x4 acc = (f32x4){0.f, 0.f, 0.f, 0.f};
#pragma unroll
            for (int kc = 0; kc < 4; kc++) {
                short8 bfr = *(const short8*)&Ks[t * 16 + l][kc * 32 + g * 8];
                acc = __builtin_amdgcn_mfma_f32_16x16x32_bf16(qf[kc], bfr, acc, 0, 0, 0);
            }
            st[t] = acc;
        }
        int rbase = q0 + wave * 16 + g * 4;
#pragma unroll
        for (int t = 0; t < 4; t++) {
            int key = kc0 + t * 16 + l;
#pragma unroll
            for (int i = 0; i < 4; i++)
                if (key > rbase + i) st[t][i] = -1e30f;
        }
        float nm[4], al[4], ps[4];
#pragma unroll
        for (int i = 0; i < 4; i++) {
            float tm = fmaxf(fmaxf(st[0][i], st[1][i]), fmaxf(st[2][i], st[3][i]));
            tm = fmaxf(tm, __shfl_xor(tm, 1));
            tm = fmaxf(tm, __shfl_xor(tm, 2));
            tm = fmaxf(tm, __shfl_xor(tm, 4));
            tm = fmaxf(tm, __shfl_xor(tm, 8));
            nm[i] = fmaxf(mrow[i], tm);
            al[i] = __expf(mrow[i] - nm[i]);
            mrow[i] = nm[i];
            ps[i] = 0.f;
        }
#pragma unroll
        for (int t = 0; t < 4; t++) {
#pragma unroll
            for (int i = 0; i < 4; i++) {
                float p = __expf(st[t][i] - nm[i]);
                ps[i] += p;
                Ps[wave][g * 4 + i][t * 16 + l] = f2bf(p);
            }
        }
#pragma unroll
        for (int i = 0; i < 4; i++) {
            float s = ps[i];
            s += __shfl_xor(s, 1);
            s += __shfl_xor(s, 2);
            s += __shfl_xor(s, 4);
            s += __shfl_xor(s, 8);
            lrow[i] = lrow[i] * al[i] + s;
#pragma unroll
            for (int n = 0; n < 8; n++) o[n][i] *= al[i];
        }
#pragma unroll
        for (int kc2 = 0; kc2 < 2; kc2++) {
            short8 pf = *(const short8*)&Ps[wave][l][kc2 * 32 + g * 8];
#pragma unroll
            for (int n = 0; n < 8; n++) {
                short8 vf = *(const short8*)&Vt[n * 16 + l][kc2 * 32 + g * 8];
                o[n] = __builtin_amdgcn_mfma_f32_16x16x32_bf16(pf, vf, o[n], 0, 0, 0);
            }
        }
    }
    float inv[4];
#pragma unroll
    for (int i = 0; i < 4; i++) inv[i] = 1.f / lrow[i];
#pragma unroll
    for (int n = 0; n < 8; n++) {
#pragma unroll
        for (int i = 0; i < 4; i++) {
            y[(size_t)(b * TT + q0 + wave * 16 + g * 4 + i) * CC + h * HD + n * 16 + l] =
                o[n][i] * inv[i];
        }
    }
}

// ---------------------------------------------------------------------------
// Launcher. Workspace (~94.5 MB):
//   xb   ushort [4096*2048] 16.78 MB
//   wb   ushort [6144*2048] 25.17 MB
//   qkvB ushort [4096*6144] 50.33 MB
//   kshB ushort [4096*128]   1.05 MB
//   vshT ushort [128*4096]   1.05 MB
//   top1 float [4096], idx int [4096]
// ---------------------------------------------------------------------------
extern "C" void kernel_launch(void* const* d_in, const int* in_sizes, int n_in,
                              void* d_out, int out_size, void* d_ws, size_t ws_size,
                              hipStream_t stream) {
    (void)in_sizes; (void)n_in; (void)out_size; (void)ws_size;
    const float* x    = (const float*)d_in[0];
    const float* Wg   = (const float*)d_in[1];
    const float* Wqkv = (const float*)d_in[2];
    float* y = (float*)d_out;

    unsigned short* xb   = (unsigned short*)d_ws;
    unsigned short* wb   = xb + (size_t)MM * CC;
    unsigned short* qkvB = wb + (size_t)QKV_N * CC;
    unsigned short* kshB = qkvB + (size_t)MM * QKV_N;
    unsigned short* vshT = kshB + (size_t)MM * HD;
    float* top1 = (float*)(vshT + (size_t)HD * MM);
    int*   idxb = (int*)(top1 + MM);

    gate_kernel<<<MM, 256, 0, stream>>>(x, Wg, idxb, top1);
    convert_bf16<<<(MM * CC / 8 + 255) / 256, 256, 0, stream>>>(x, xb, MM * CC / 8);
    convert_bf16<<<(QKV_N * CC / 8 + 255) / 256, 256, 0, stream>>>(Wqkv, wb, QKV_N * CC / 8);
    qkv_gemm<<<dim3(QKV_N / 128, MM / 128), 256, 0, stream>>>(xb, wb, qkvB);
    kv_gather2<<<MM / 64, 256, 0, stream>>>(qkvB, idxb, top1, kshB, vshT);
    attn_mfma<<<BB * HH * (TT / 64), 256, 0, stream>>>(qkvB, kshB, vshT, y);
}

// Round 4
// 492.806 us; speedup vs baseline: 14.1087x; 1.1295x over previous
//
#include <hip/hip_runtime.h>
#include <math.h>
#include <cstddef>

// Problem constants
#define BB 2
#define TT 2048
#define CC 2048
#define HH 16
#define HD 128
#define MM (BB * TT)   // 4096 tokens
#define QKV_N 6144
#define BK 32

typedef __attribute__((ext_vector_type(8))) short short8;
typedef __attribute__((ext_vector_type(4))) float f32x4;

__device__ __forceinline__ unsigned short f2bf(float f) {
    union { float f; unsigned int u; } v; v.f = f;
    unsigned int r = v.u + 0x7FFFu + ((v.u >> 16) & 1u);  // RNE
    return (unsigned short)(r >> 16);
}
__device__ __forceinline__ float bf2f(unsigned short s) {
    union { unsigned int u; float f; } v; v.u = ((unsigned int)s) << 16;
    return v.f;
}
__device__ __forceinline__ void gload16(const void* g, void* l) {
    __builtin_amdgcn_global_load_lds(
        (const __attribute__((address_space(1))) unsigned int*)g,
        (__attribute__((address_space(3))) unsigned int*)l, 16, 0, 0);
}

// ---------------------------------------------------------------------------
// K1: gating. One block per token. fp32 (argmax ties must match np).
// ---------------------------------------------------------------------------
__global__ __launch_bounds__(256) void gate_kernel(const float* __restrict__ x,
                                                   const float* __restrict__ Wg,
                                                   int* __restrict__ idxbuf,
                                                   float* __restrict__ top1buf) {
    int m = blockIdx.x;
    int tid = threadIdx.x;
    int h = tid >> 4;
    int j = tid & 15;
    const float4* xr = (const float4*)(x + (size_t)m * CC);
    const float4* wr = (const float4*)(Wg + (size_t)h * CC);
    float acc = 0.f;
#pragma unroll 8
    for (int i = 0; i < CC / 4; i += 16) {
        float4 a = xr[i + j];
        float4 b = wr[i + j];
        acc += a.x * b.x + a.y * b.y + a.z * b.z + a.w * b.w;
    }
    for (int off = 8; off > 0; off >>= 1) acc += __shfl_down(acc, off, 16);
    __shared__ float logits[HH];
    if (j == 0) logits[h] = acc;
    __syncthreads();
    if (tid == 0) {
        float zmax = logits[0];
        int best = 0;
        for (int i = 1; i < HH; i++) {
            if (logits[i] > zmax) { zmax = logits[i]; best = i; }
        }
        float s = 0.f;
        for (int i = 0; i < HH; i++) s += expf(logits[i] - zmax);
        idxbuf[m] = best;
        top1buf[m] = 1.0f / s;
    }
}

// ---------------------------------------------------------------------------
// K2: fp32 -> bf16 convert (8 elems/thread, 16B stores).
// ---------------------------------------------------------------------------
__global__ __launch_bounds__(256) void convert_bf16(const float* __restrict__ src,
                                                    unsigned short* __restrict__ dst,
                                                    int n8) {
    int i = blockIdx.x * 256 + threadIdx.x;
    if (i >= n8) return;
    const float4* s4 = (const float4*)src;
    float4 a = s4[i * 2], b = s4[i * 2 + 1];
    union { unsigned short s[8]; uint4 u; } pk;
    pk.s[0] = f2bf(a.x); pk.s[1] = f2bf(a.y); pk.s[2] = f2bf(a.z); pk.s[3] = f2bf(a.w);
    pk.s[4] = f2bf(b.x); pk.s[5] = f2bf(b.y); pk.s[6] = f2bf(b.z); pk.s[7] = f2bf(b.w);
    ((uint4*)dst)[i] = pk.u;
}

// ---------------------------------------------------------------------------
// K3: qkv = xb @ wbT, bf16 MFMA GEMM (m97 structure).
// ---------------------------------------------------------------------------
__global__ __launch_bounds__(256) void qkv_gemm(const unsigned short* __restrict__ A,  // [M][2048] bf16
                                                const unsigned short* __restrict__ Bm, // [N][2048] bf16
                                                unsigned short* __restrict__ C) {      // [M][6144] bf16
    __shared__ unsigned short As[128 * BK];  // 8 KB
    __shared__ unsigned short Bs[128 * BK];  // 8 KB
    int tid = threadIdx.x;
    int wave = tid >> 6, lane = tid & 63;
    int l = lane & 15, g = lane >> 4;
    int m0 = blockIdx.y * 128, n0 = blockIdx.x * 128;
    int wr = wave >> 1, wc = wave & 1;

    f32x4 acc[4][4];
#pragma unroll
    for (int i = 0; i < 4; i++)
#pragma unroll
        for (int j = 0; j < 4; j++) acc[i][j] = (f32x4){0.f, 0.f, 0.f, 0.f};

    int srow = lane >> 2;
    int scol = (lane & 3) * 8;
    const unsigned short* aB0 = A + (size_t)(m0 + wave * 32 + srow) * 2048 + scol;
    const unsigned short* bB0 = Bm + (size_t)(n0 + wave * 32 + srow) * 2048 + scol;
    unsigned short* aL0 = &As[wave * 1024];
    unsigned short* bL0 = &Bs[wave * 1024];

    for (int k0 = 0; k0 < 2048; k0 += BK) {
        __syncthreads();
        gload16(aB0 + k0, aL0);
        gload16(aB0 + k0 + (size_t)16 * 2048, aL0 + 512);
        gload16(bB0 + k0, bL0);
        gload16(bB0 + k0 + (size_t)16 * 2048, bL0 + 512);
        __syncthreads();
        short8 af[4], bf[4];
#pragma unroll
        for (int i = 0; i < 4; i++)
            af[i] = *(const short8*)&As[(wr * 64 + i * 16 + l) * BK + g * 8];
#pragma unroll
        for (int j = 0; j < 4; j++)
            bf[j] = *(const short8*)&Bs[(wc * 64 + j * 16 + l) * BK + g * 8];
#pragma unroll
        for (int i = 0; i < 4; i++)
#pragma unroll
            for (int j = 0; j < 4; j++)
                acc[i][j] = __builtin_amdgcn_mfma_f32_16x16x32_bf16(af[i], bf[j], acc[i][j], 0, 0, 0);
    }

    const float qscale = 0.08838834764831845f;  // 1/sqrt(128)
#pragma unroll
    for (int j = 0; j < 4; j++) {
        int col = n0 + wc * 64 + j * 16 + l;
        float s = (col < 2048) ? qscale : 1.0f;
#pragma unroll
        for (int i = 0; i < 4; i++) {
            int row = m0 + wr * 64 + i * 16 + g * 4;
#pragma unroll
            for (int r = 0; r < 4; r++)
                C[(size_t)(row + r) * QKV_N + col] = f2bf(acc[i][j][r] * s);
        }
    }
}

// ---------------------------------------------------------------------------
// K4: gather selected head's k/v from qkv buffer.
// ---------------------------------------------------------------------------
__global__ __launch_bounds__(256) void kv_gather2(const unsigned short* __restrict__ qkv,
                                                  const int* __restrict__ idxb,
                                                  const float* __restrict__ top1,
                                                  unsigned short* __restrict__ kshB,
                                                  unsigned short* __restrict__ vshT) {
    __shared__ unsigned short Vs[64][136];
    int m0 = blockIdx.x * 64;
    int tid = threadIdx.x;
    int tok = tid >> 2;
    int c4 = tid & 3;
    int m = m0 + tok;
    int hs = idxb[m];
    float tv = top1[m];
    const uint4* krow = (const uint4*)(qkv + (size_t)m * QKV_N + 2048 + hs * 128);
    const uint4* vrow = (const uint4*)(qkv + (size_t)m * QKV_N + 4096 + hs * 128);
    uint4* kdst = (uint4*)(kshB + (size_t)m * HD);
#pragma unroll
    for (int u = 0; u < 4; u++) kdst[c4 * 4 + u] = krow[c4 * 4 + u];
#pragma unroll
    for (int u = 0; u < 4; u++) {
        uint4 d = vrow[c4 * 4 + u];
        unsigned short* ss = (unsigned short*)&d;
        union { unsigned short s[8]; uint4 u4; } pk;
#pragma unroll
        for (int e = 0; e < 8; e++) pk.s[e] = f2bf(bf2f(ss[e]) * tv);
        *(uint4*)&Vs[tok][(c4 * 4 + u) * 8] = pk.u4;
    }
    __syncthreads();
    int d = tid >> 1, half = tid & 1;
#pragma unroll
    for (int u = 0; u < 4; u++) {
        union { unsigned short s[8]; uint4 u4; } pk;
#pragma unroll
        for (int e = 0; e < 8; e++) pk.s[e] = Vs[half * 32 + u * 8 + e][d];
        *(uint4*)(vshT + (size_t)d * MM + m0 + half * 32 + u * 8) = pk.u4;
    }
}

// ---------------------------------------------------------------------------
// K5: MFMA bf16 flash attention, fixed-shift softmax (no online max/rescale).
// p = exp(s - 30); row-sum l accumulated via ones-column MFMA (register-const
// B-frag, lands in o8 col 0). Mask applied only in the diagonal chunk.
// Final: y = o / l. Numerically identical to softmax (shift cancels).
// ---------------------------------------------------------------------------
__global__ __launch_bounds__(256) void attn_mfma(const unsigned short* __restrict__ qb,   // [M][6144] bf16, q pre-scaled
                                                 const unsigned short* __restrict__ kb,   // [M][128] bf16
                                                 const unsigned short* __restrict__ vtb,  // [128][M] bf16
                                                 float* __restrict__ y) {                 // [M][2048] fp32
    __shared__ unsigned short Ks[64][136];
    __shared__ unsigned short Vt[128][72];
    __shared__ unsigned short Ps[4][16][72];

    int bid = blockIdx.x;
    int qt = 31 - (bid & 31);          // longest q-tiles first
    int bh = bid >> 5;
    int h = bh & 15;
    int b = bh >> 4;
    int q0 = qt * 64;
    int tid = threadIdx.x;
    int wave = tid >> 6;
    int lane = tid & 63;
    int l = lane & 15;
    int g = lane >> 4;

    short8 qf[4];
    {
        const unsigned short* qrowp = qb + (size_t)(b * TT + q0 + wave * 16 + l) * QKV_N + h * HD;
#pragma unroll
        for (int kc = 0; kc < 4; kc++)
            qf[kc] = *(const short8*)(qrowp + kc * 32 + g * 8);
    }

    // ones-column B-frag for the l (row-sum) MFMA: B[n][k] = (n==0) ? 1 : 0
    short8 onesf;
    {
        short v = (l == 0) ? (short)0x3F80 : (short)0;
#pragma unroll
        for (int e = 0; e < 8; e++) onesf[e] = v;
    }

    f32x4 o[8];
#pragma unroll
    for (int n = 0; n < 8; n++) o[n] = (f32x4){0.f, 0.f, 0.f, 0.f};
    f32x4 o8 = (f32x4){0.f, 0.f, 0.f, 0.f};   // l accumulator (col 0)

    int rbase = q0 + wave * 16 + g * 4;
    for (int c = 0; c <= qt; c++) {
        int kc0 = c * 64;
        __syncthreads();
#pragma unroll
        for (int rep = 0; rep < 4; rep++) {
            int f = tid + rep * 256;
            int row = f >> 4, c8 = f & 15;
            uint4 d = *(const uint4*)(kb + (size_t)(b * TT + kc0 + row) * HD + c8 * 8);
            *(uint4*)&Ks[row][c8 * 8] = d;
        }
#pragma unroll
        for (int rep = 0; rep < 4; rep++) {
            int f = tid + rep * 256;
            int dd = f >> 3, k8 = f & 7;
            uint4 d = *(const uint4*)(vtb + (size_t)dd * MM + b * TT + kc0 + k8 * 8);
            *(uint4*)&Vt[dd][k8 * 8] = d;
        }
        __syncthreads();

        // S = Q K^T
        f32x4 st[4];
#pragma unroll
        for (int t = 0; t < 4; t++) {
            f32x4 acc = (f32x4){0.f, 0.f, 0.f, 0.f};
#pragma unroll
            for (int kc = 0; kc < 4; kc++) {
                short8 bfr = *(const short8*)&Ks[t * 16 + l][kc * 32 + g * 8];
                acc = __builtin_amdgcn_mfma_f32_16x16x32_bf16(qf[kc], bfr, acc, 0, 0, 0);
            }
            st[t] = acc;
        }
        if (c == qt) {  // diagonal chunk: causal mask (wave-uniform branch)
#pragma unroll
            for (int t = 0; t < 4; t++) {
                int key = kc0 + t * 16 + l;
#pragma unroll
                for (int i = 0; i < 4; i++)
                    if (key > rbase + i) st[t][i] = -1e30f;
            }
        }
        // p = exp(s - 30), straight to LDS in A-layout
#pragma unroll
        for (int t = 0; t < 4; t++) {
#pragma unroll
            for (int i = 0; i < 4; i++) {
                float p = __expf(st[t][i] - 30.f);
                Ps[wave][g * 4 + i][t * 16 + l] = f2bf(p);
            }
        }
        // O += P V ; l += P (ones column). Same-wave DS ordering: no barrier.
#pragma unroll
        for (int kc2 = 0; kc2 < 2; kc2++) {
            short8 pf = *(const short8*)&Ps[wave][l][kc2 * 32 + g * 8];
#pragma unroll
            for (int n = 0; n < 8; n++) {
                short8 vf = *(const short8*)&Vt[n * 16 + l][kc2 * 32 + g * 8];
                o[n] = __builtin_amdgcn_mfma_f32_16x16x32_bf16(pf, vf, o[n], 0, 0, 0);
            }
            o8 = __builtin_amdgcn_mfma_f32_16x16x32_bf16(pf, onesf, o8, 0, 0, 0);
        }
    }
    // l for row g*4+i sits in lane (g*16, i); broadcast across the 16 l-lanes
    float inv[4];
#pragma unroll
    for (int i = 0; i < 4; i++) {
        float lv = __shfl(o8[i], lane & 48);
        inv[i] = 1.f / lv;
    }
#pragma unroll
    for (int n = 0; n < 8; n++) {
#pragma unroll
        for (int i = 0; i < 4; i++) {
            y[(size_t)(b * TT + q0 + wave * 16 + g * 4 + i) * CC + h * HD + n * 16 + l] =
                o[n][i] * inv[i];
        }
    }
}

// ---------------------------------------------------------------------------
// Launcher. Workspace (~94.5 MB).
// ---------------------------------------------------------------------------
extern "C" void kernel_launch(void* const* d_in, const int* in_sizes, int n_in,
                              void* d_out, int out_size, void* d_ws, size_t ws_size,
                              hipStream_t stream) {
    (void)in_sizes; (void)n_in; (void)out_size; (void)ws_size;
    const float* x    = (const float*)d_in[0];
    const float* Wg   = (const float*)d_in[1];
    const float* Wqkv = (const float*)d_in[2];
    float* y = (float*)d_out;

    unsigned short* xb   = (unsigned short*)d_ws;
    unsigned short* wb   = xb + (size_t)MM * CC;
    unsigned short* qkvB = wb + (size_t)QKV_N * CC;
    unsigned short* kshB = qkvB + (size_t)MM * QKV_N;
    unsigned short* vshT = kshB + (size_t)MM * HD;
    float* top1 = (float*)(vshT + (size_t)HD * MM);
    int*   idxb = (int*)(top1 + MM);

    gate_kernel<<<MM, 256, 0, stream>>>(x, Wg, idxb, top1);
    convert_bf16<<<(MM * CC / 8 + 255) / 256, 256, 0, stream>>>(x, xb, MM * CC / 8);
    convert_bf16<<<(QKV_N * CC / 8 + 255) / 256, 256, 0, stream>>>(Wqkv, wb, QKV_N * CC / 8);
    qkv_gemm<<<dim3(QKV_N / 128, MM / 128), 256, 0, stream>>>(xb, wb, qkvB);
    kv_gather2<<<MM / 64, 256, 0, stream>>>(qkvB, idxb, top1, kshB, vshT);
    attn_mfma<<<BB * HH * (TT / 64), 256, 0, stream>>>(qkvB, kshB, vshT, y);
}